// Round 3
// baseline (230.273 us; speedup 1.0000x reference)
//
#include <hip/hip_runtime.h>

// Causal flash attention, B=4 L=S=2048 H=8 E=D=64, fp32 in/out, bf16 MFMA.
// Round 10: (1) sched_barrier(0)-pinned per-tile pipeline: [issue V(kt)+K(kt+1)
// loads][QK mfma][softmax][pack+PV]. Round-9 VGPR=92 proved the compiler sank
// the prefetches to use sites (live set needs ~150) -> exposed L2 latency per
// tile. Named A/B K-buffers in an unrolled-by-2 loop (rule #20), LB(128,3)
// caps VGPR at ~168 (grid gives 12 waves/CU = 3/SIMD, cap matches).
// (2) VALU trim: P-pack via v_cvt_pk_bf16_f32 (48->16 ops), v_max3-friendly
// max tree, flat sum tree (softmax was ~380 VALU ops/tile = dominant issue
// load vs 128 MFMA cycles). (3) paired blocks take equal strips (2j,2j+1).
// Math/P-layout/merge identical to round 9 (hardware-validated).

typedef unsigned short u16;
typedef unsigned int   u32;
typedef short short8   __attribute__((ext_vector_type(8)));
typedef float floatx16 __attribute__((ext_vector_type(16)));
typedef u32 u32x4      __attribute__((ext_vector_type(4)));

#define B_ 4
#define L_ 2048
#define S_ 2048
#define H_ 8
#define E_ 64
#define D_ 64

// round-half-up fp32->bf16 pair, lo in low 16 bits
static __device__ __forceinline__ u32 pack2(float lo, float hi) {
    const u32 a = __float_as_uint(lo) + 0x8000u;
    const u32 b = __float_as_uint(hi) + 0x8000u;
    return __builtin_amdgcn_perm(b, a, 0x07060302u);
}
static __device__ __forceinline__ u16 bf16c(float x) {
    return (u16)((__float_as_uint(x) + 0x8000u) >> 16);
}
// v_cvt_pk_bf16_f32: one instruction packs 2 f32 -> 2 bf16 (RNE), lo first
static __device__ __forceinline__ u32 cvtpk(float lo, float hi) {
    u32 r;
    asm("v_cvt_pk_bf16_f32 %0, %1, %2" : "=v"(r) : "v"(lo), "v"(hi));
    return r;
}
// v_permlane32_swap_b32: a.hi32lanes <-> b.lo32lanes
static __device__ __forceinline__ void pl32swap(u32& a, u32& b) {
    asm("v_permlane32_swap_b32 %0, %1" : "+v"(a), "+v"(b));
}
static __device__ __forceinline__ floatx16 zero16() {
    floatx16 z;
    #pragma unroll
    for (int i = 0; i < 16; i++) z[i] = 0.f;
    return z;
}

// ---------------- pre-pass: fp32 -> bf16, FRAG-MAJOR tiles ----------------
// Kc tile (per bh,kt; 4096 u16): [F=mt*4+ks][lane=hi*32+l31][j]
//   holds K[b][s=kt*64+mt*32+l31][h][e=ks*16+hi*8+j]
// Vt tile (per bh,kt; 4096 u16): [F=nt*4+ks][lane=hi*32+l31][j]
//   holds V[b][s=kt*64+ks*16+hi*8+j][h][d=nt*32+l31]
__global__ __launch_bounds__(256)
void cvt_kernel(const float* __restrict__ k, const float* __restrict__ v,
                u16* __restrict__ kc, u16* __restrict__ vt)
{
    __shared__ u16 Lt[64 * 72];
    const int bx = blockIdx.x, t = threadIdx.x;
    const int tile = bx & 1023;
    const int kt = tile & 31, h = (tile >> 5) & 7, b = tile >> 8;
    const int F  = t >> 5;
    const int hi = (t >> 4) & 1;
    const int l0 = (t & 15) * 2;

    if (bx < 1024) {
        const int mt = F >> 2, ks = F & 3;
        const int s  = kt * 64 + mt * 32 + l0;
        const int e  = ks * 16 + hi * 8;
        const float* p0 = k + (((size_t)(b * S_ + s)) * H_ + h) * E_ + e;
        const float4 a0 = ((const float4*)p0)[0], a1 = ((const float4*)p0)[1];
        const float* p1 = p0 + H_ * E_;
        const float4 b0 = ((const float4*)p1)[0], b1 = ((const float4*)p1)[1];
        u16* dst = kc + ((size_t)(b * 8 + h)) * 131072 + (size_t)kt * 4096 + t * 16;
        *(u32x4*)dst = (u32x4){pack2(a0.x, a0.y), pack2(a0.z, a0.w),
                               pack2(a1.x, a1.y), pack2(a1.z, a1.w)};
        *(u32x4*)(dst + 8) = (u32x4){pack2(b0.x, b0.y), pack2(b0.z, b0.w),
                                     pack2(b1.x, b1.y), pack2(b1.z, b1.w)};
    } else {
        {
            const int i  = t >> 2;
            const int d0 = (t & 3) * 16;
            const float* vp = v + (((size_t)(b * S_ + kt * 64 + i)) * H_ + h) * D_ + d0;
            const float4 a0 = ((const float4*)vp)[0], a1 = ((const float4*)vp)[1];
            const float4 a2 = ((const float4*)vp)[2], a3 = ((const float4*)vp)[3];
            const float va[16] = {a0.x,a0.y,a0.z,a0.w, a1.x,a1.y,a1.z,a1.w,
                                  a2.x,a2.y,a2.z,a2.w, a3.x,a3.y,a3.z,a3.w};
            #pragma unroll
            for (int jj = 0; jj < 16; jj++) Lt[(d0 + jj) * 72 + i] = bf16c(va[jj]);
        }
        __syncthreads();
        {
            const int nt = F >> 2, ks = F & 3;
            const int d1 = nt * 32 + l0;
            u16* dst = vt + ((size_t)(b * 8 + h)) * 131072 + (size_t)kt * 4096 + t * 16;
            *(u32x4*)dst       = *(const u32x4*)&Lt[(d1    ) * 72 + ks * 16 + hi * 8];
            *(u32x4*)(dst + 8) = *(const u32x4*)&Lt[(d1 + 1) * 72 + ks * 16 + hi * 8];
        }
    }
}

// One K-tile step. Region order pinned by sched_barrier(0):
//   [issue V(kt) + K(kt+1)->NXTK] | [QK mfma from CURK] | [softmax] | [pack+PV]
#define TILE_STEP(CURK, NXTK)                                                   \
{                                                                               \
    _Pragma("unroll")                                                           \
    for (int ks = 0; ks < 4; ks++) {                                            \
        vf[0][ks] = loadV(kt, 0, ks);                                           \
        vf[1][ks] = loadV(kt, 1, ks);                                           \
    }                                                                           \
    if (kt < ktend) {                                                           \
        _Pragma("unroll")                                                       \
        for (int ks = 0; ks < 4; ks++) {                                        \
            NXTK[0][ks] = loadK(kt + 1, 0, ks);                                 \
            NXTK[1][ks] = loadK(kt + 1, 1, ks);                                 \
        }                                                                       \
    }                                                                           \
    __builtin_amdgcn_sched_barrier(0);                                          \
    floatx16 sac0, sac1;                                                        \
    {                                                                           \
        __builtin_amdgcn_s_setprio(1);                                          \
        floatx16 c0 = zero16(), c1 = zero16();                                  \
        _Pragma("unroll")                                                       \
        for (int ks = 0; ks < 4; ks++) {                                        \
            c0 = __builtin_amdgcn_mfma_f32_32x32x16_bf16(CURK[0][ks], qf[ks], c0, 0, 0, 0); \
            c1 = __builtin_amdgcn_mfma_f32_32x32x16_bf16(CURK[1][ks], qf[ks], c1, 0, 0, 0); \
        }                                                                       \
        __builtin_amdgcn_s_setprio(0);                                          \
        sac0 = c0; sac1 = c1;                                                   \
    }                                                                           \
    __builtin_amdgcn_sched_barrier(0);                                          \
    if (diag && kt == ktend) {                                                  \
        const int qg = q0 + l31;                                                \
        _Pragma("unroll")                                                       \
        for (int r = 0; r < 16; r++) {                                          \
            const int key0 = kt * 64 + (r & 3) + (r >> 2) * 8 + hi * 4;         \
            if (key0 > qg)      sac0[r] = -1e30f;                               \
            if (key0 + 32 > qg) sac1[r] = -1e30f;                               \
        }                                                                       \
    }                                                                           \
    float m01[8];                                                               \
    _Pragma("unroll")                                                           \
    for (int r = 0; r < 8; r++)                                                 \
        m01[r] = fmaxf(fmaxf(sac0[r], sac0[r + 8]), fmaxf(sac1[r], sac1[r + 8])); \
    const float t0  = fmaxf(fmaxf(m01[0], m01[1]), m01[2]);                     \
    const float t1  = fmaxf(fmaxf(m01[3], m01[4]), m01[5]);                     \
    const float t2  = fmaxf(fmaxf(m01[6], m01[7]), t0);                         \
    const float mxl = fmaxf(t1, t2);                                            \
    const float mx  = fmaxf(mxl, __shfl_xor(mxl, 32));                          \
    const bool defer = __all(mx - m_run <= 8.0f) != 0;                          \
    if (!defer) {                                                               \
        const float mnew  = fmaxf(m_run, mx);                                   \
        const float alpha = exp2f(m_run - mnew);                                \
        m_run = mnew;                                                           \
        l_run *= alpha;                                                         \
        _Pragma("unroll")                                                       \
        for (int r = 0; r < 16; r++) { occ[0][r] *= alpha; occ[1][r] *= alpha; } \
    }                                                                           \
    _Pragma("unroll")                                                           \
    for (int r = 0; r < 16; r++) {                                              \
        sac0[r] = exp2f(sac0[r] - m_run);                                       \
        sac1[r] = exp2f(sac1[r] - m_run);                                       \
    }                                                                           \
    float sm[8];                                                                \
    _Pragma("unroll")                                                           \
    for (int r = 0; r < 8; r++)                                                 \
        sm[r] = (sac0[r] + sac0[r + 8]) + (sac1[r] + sac1[r + 8]);              \
    const float u0 = (sm[0] + sm[1]) + (sm[2] + sm[3]);                         \
    const float u1 = (sm[4] + sm[5]) + (sm[6] + sm[7]);                         \
    const float pssum = u0 + u1;                                                \
    l_run += pssum + __shfl_xor(pssum, 32);                                     \
    __builtin_amdgcn_sched_barrier(0);                                          \
    u32 pk0[8], pk1[8];                                                         \
    _Pragma("unroll")                                                           \
    for (int r2 = 0; r2 < 4; r2++) {                                            \
        pk0[2 * r2 + 0] = cvtpk(sac0[4 * r2 + 0], sac0[4 * r2 + 1]);            \
        pk0[2 * r2 + 1] = cvtpk(sac0[4 * r2 + 2], sac0[4 * r2 + 3]);            \
        pk1[2 * r2 + 0] = cvtpk(sac1[4 * r2 + 0], sac1[4 * r2 + 1]);            \
        pk1[2 * r2 + 1] = cvtpk(sac1[4 * r2 + 2], sac1[4 * r2 + 3]);            \
    }                                                                           \
    __builtin_amdgcn_s_setprio(1);                                              \
    _Pragma("unroll")                                                           \
    for (int ks = 0; ks < 4; ks++) {                                            \
        const int u = (ks & 1) * 4;                                             \
        u32 w0, w1, w2, w3;                                                     \
        if (ks < 2) { w0 = pk0[u]; w1 = pk0[u + 1]; w2 = pk0[u + 2]; w3 = pk0[u + 3]; } \
        else        { w0 = pk1[u]; w1 = pk1[u + 1]; w2 = pk1[u + 2]; w3 = pk1[u + 3]; } \
        pl32swap(w0, w2);                                                       \
        pl32swap(w1, w3);                                                       \
        const u32x4 pw = {w0, w1, w2, w3};                                      \
        const short8 pf = __builtin_bit_cast(short8, pw);                       \
        occ[0] = __builtin_amdgcn_mfma_f32_32x32x16_bf16(vf[0][ks], pf, occ[0], 0, 0, 0); \
        occ[1] = __builtin_amdgcn_mfma_f32_32x32x16_bf16(vf[1][ks], pf, occ[1], 0, 0, 0); \
    }                                                                           \
    __builtin_amdgcn_s_setprio(0);                                              \
}

// ---------------- main kernel ----------------
// Grid 1536 x 128thr (2 waves). bx<1024: SPLIT block -- both waves on strip
// s32=63-(bx>>5), wave0 K-tiles [0,mid), wave1 [mid,klast] (+diag), LDS merge.
// bx>=1024: PAIRED block -- wave w on strip 2*jj+w (equal tile counts).
template<int SRC>
__global__ __launch_bounds__(128, 3)
void fa_kernel(const float* __restrict__ q, const float* __restrict__ kk,
               const float* __restrict__ vv, const u16* __restrict__ kc,
               const u16* __restrict__ vt, float* __restrict__ out)
{
    __shared__ float Ls[64 * 33 + 128];   // partial O (padded) + m + l

    const int tid  = threadIdx.x;
    const int w    = tid >> 6;
    const int lane = tid & 63;
    const int l31  = lane & 31;
    const int hi   = lane >> 5;

    const int bx = blockIdx.x;
    int h, b, s32, kt0, ktend;
    bool split, diag;
    if (bx < 1024) {
        split = true;
        h = bx & 7; b = (bx >> 3) & 3;
        s32 = 63 - (bx >> 5);
        const int klast = s32 >> 1;
        const int mid   = (klast + 1) >> 1;
        if (w == 0) { kt0 = 0;   ktend = mid - 1; diag = false; }
        else        { kt0 = mid; ktend = klast;   diag = true;  }
    } else {
        split = false; diag = true;
        const int idx = bx - 1024;
        h = idx & 7; b = (idx >> 3) & 3;
        const int jj = 15 - (idx >> 5);   // big pairs dispatched first
        s32 = 2 * jj + w;                 // equal T = jj+1 for both waves
        kt0 = 0; ktend = jj;
    }
    const int q0 = s32 * 32;

    const float kscale = 0.18033688011112042f; // (1/sqrt(64)) * log2(e)

    // ---- Q frags (B-operand of S^T = K*Q^T), kscale folded ----
    const float* qptr = q + (((size_t)b * L_ + q0 + l31) * H_ + h) * E_ + hi * 8;
    short8 qf[4];
    #pragma unroll
    for (int ks = 0; ks < 4; ks++) {
        const float4 a0 = *(const float4*)(qptr + ks * 16);
        const float4 a1 = *(const float4*)(qptr + ks * 16 + 4);
        const u32x4 u = {pack2(a0.x * kscale, a0.y * kscale), pack2(a0.z * kscale, a0.w * kscale),
                         pack2(a1.x * kscale, a1.y * kscale), pack2(a1.z * kscale, a1.w * kscale)};
        qf[ks] = __builtin_bit_cast(short8, u);
    }

    const size_t bh = (size_t)(b * 8 + h);
    const u16* kcb = kc + bh * 131072;
    const u16* vtb = vt + bh * 131072;

    auto loadK = [&](int kt, int mt, int ks) -> short8 {
        if constexpr (SRC == 0) {
            const u32x4 u = *(const u32x4*)&kcb[(size_t)kt * 4096 + (mt * 4 + ks) * 512 + lane * 8];
            return __builtin_bit_cast(short8, u);
        } else {
            const float* p = kk + (((size_t)b * S_ + kt * 64 + mt * 32 + l31) * H_ + h) * E_ + ks * 16 + hi * 8;
            const float4 a0 = *(const float4*)p;
            const float4 a1 = *(const float4*)(p + 4);
            const u32x4 u = {pack2(a0.x, a0.y), pack2(a0.z, a0.w), pack2(a1.x, a1.y), pack2(a1.z, a1.w)};
            return __builtin_bit_cast(short8, u);
        }
    };
    auto loadV = [&](int kt, int nt, int ks) -> short8 {
        if constexpr (SRC == 0) {
            const u32x4 u = *(const u32x4*)&vtb[(size_t)kt * 4096 + (nt * 4 + ks) * 512 + lane * 8];
            return __builtin_bit_cast(short8, u);
        } else {
            float f[8];
            #pragma unroll
            for (int jj2 = 0; jj2 < 8; jj2++)
                f[jj2] = vv[(((size_t)b * S_ + kt * 64 + ks * 16 + hi * 8 + jj2) * H_ + h) * D_ + nt * 32 + l31];
            const u32x4 u = {pack2(f[0], f[1]), pack2(f[2], f[3]), pack2(f[4], f[5]), pack2(f[6], f[7])};
            return __builtin_bit_cast(short8, u);
        }
    };

    floatx16 occ[2] = {zero16(), zero16()};  // O^T: col = q = l31
    float m_run = -1e30f, l_run = 0.f;

    short8 kfA[2][4], kfB[2][4], vf[2][4];
    #pragma unroll
    for (int ks = 0; ks < 4; ks++) { kfA[0][ks] = loadK(kt0, 0, ks); kfA[1][ks] = loadK(kt0, 1, ks); }

    int kt = kt0;
    for (;;) {
        TILE_STEP(kfA, kfB)
        if (kt == ktend) break;
        ++kt;
        TILE_STEP(kfB, kfA)
        if (kt == ktend) break;
        ++kt;
    }

    // ---- epilogue ----
    if (split) {
        if (w == 1) {
            #pragma unroll
            for (int nt = 0; nt < 2; nt++)
                #pragma unroll
                for (int r = 0; r < 16; r++) Ls[lane * 33 + nt * 16 + r] = occ[nt][r];
            Ls[2112 + lane] = m_run;
            Ls[2176 + lane] = l_run;
        }
        __syncthreads();
        if (w == 0) {
            const float mB = Ls[2112 + lane], lB = Ls[2176 + lane];
            const float m  = fmaxf(m_run, mB);
            const float aA = exp2f(m_run - m), aB = exp2f(mB - m);
            const float inv = 1.0f / (l_run * aA + lB * aB);
            float* op = out + (((size_t)b * L_ + q0 + l31) * H_ + h) * D_;
            #pragma unroll
            for (int nt = 0; nt < 2; nt++)
                #pragma unroll
                for (int r2 = 0; r2 < 4; r2++) {
                    const float4 o = {
                        (occ[nt][4 * r2 + 0] * aA + Ls[lane * 33 + nt * 16 + 4 * r2 + 0] * aB) * inv,
                        (occ[nt][4 * r2 + 1] * aA + Ls[lane * 33 + nt * 16 + 4 * r2 + 1] * aB) * inv,
                        (occ[nt][4 * r2 + 2] * aA + Ls[lane * 33 + nt * 16 + 4 * r2 + 2] * aB) * inv,
                        (occ[nt][4 * r2 + 3] * aA + Ls[lane * 33 + nt * 16 + 4 * r2 + 3] * aB) * inv};
                    *(float4*)(op + nt * 32 + r2 * 8 + hi * 4) = o;
                }
        }
    } else {
        const float inv = 1.0f / l_run;
        float* op = out + (((size_t)b * L_ + q0 + l31) * H_ + h) * D_;
        #pragma unroll
        for (int nt = 0; nt < 2; nt++)
            #pragma unroll
            for (int r2 = 0; r2 < 4; r2++) {
                const float4 o = {occ[nt][4 * r2 + 0] * inv, occ[nt][4 * r2 + 1] * inv,
                                  occ[nt][4 * r2 + 2] * inv, occ[nt][4 * r2 + 3] * inv};
                *(float4*)(op + nt * 32 + r2 * 8 + hi * 4) = o;
            }
    }
}

extern "C" void kernel_launch(void* const* d_in, const int* in_sizes, int n_in,
                              void* d_out, int out_size, void* d_ws, size_t ws_size,
                              hipStream_t stream) {
    const float* q = (const float*)d_in[0];
    const float* k = (const float*)d_in[1];
    const float* v = (const float*)d_in[2];
    // d_in[3] = attn_mask: fixed causal triu -> handled analytically in-kernel.
    float* out = (float*)d_out;

    const size_t elems = (size_t)B_ * H_ * S_ * E_;   // per tensor (u16 count)
    const size_t need  = elems * 2 * 2;               // Kc + Vt, bf16
    if (d_ws != nullptr && ws_size >= need) {
        u16* kc = (u16*)d_ws;
        u16* vt = kc + elems;
        cvt_kernel<<<dim3(2048), dim3(256), 0, stream>>>(k, v, kc, vt);
        fa_kernel<0><<<dim3(1536), dim3(128), 0, stream>>>(q, k, v, kc, vt, out);
    } else {
        fa_kernel<1><<<dim3(1536), dim3(128), 0, stream>>>(q, k, v, nullptr, nullptr, out);
    }
}

// Round 7
// 153.142 us; speedup vs baseline: 1.5037x; 1.5037x over previous
//
#include <hip/hip_runtime.h>

// Causal flash attention, B=4 L=S=2048 H=8 E=D=64, fp32 in/out, bf16 MFMA.
// Round 14 = round 13 with the causal-mask trigger FIXED. Rounds 12/13 failed
// deterministically (absmax 1.447 both runs): the mask condition
// `kt*64+63 > qlim(=q0+31)` is FALSE on the diagonal tile of waves 1 and 3
// (their last row is tile-aligned-1, e.g. qlim=128j+63 vs tile last key
// 128j+63), so those waves attended to future keys. Correct trigger is
// "tile's last key > FIRST row": kt*64+63 > q0  <=>  kt >= (q0+31)>>6.
//  - Block = 256 thr = 4 waves = 128-row q-super-strip; wave w owns 32 rows.
//    All 4 waves consume the SAME k-tiles -> K/V staged ONCE per block into
//    LDS via async global_load_lds (frag-major layout is lane-linear = the
//    gload_lds dest constraint; ds_read_b128 conflict-free by construction).
//  - Pipeline per tile: [stage kt+1 async][s_waitcnt vmcnt(4)][s_barrier]
//    [SCHED_FENCE][compute kt][SCHED_FENCE][s_barrier]. Raw s_barrier (NOT
//    __syncthreads: it drains vmcnt(0) and kills the pipeline).
//  - Balanced CU pairing: first 256 blocks j=15..8, last 256 j=0..7 -> each
//    CU hosts one long + one complementary short block = 34 tiles/CU.
//  - Per-wave tile math is round-9 verbatim (HW-verified, 63us): swapped
//    QK^T, in-lane softmax, pack2+permlane32_swap P-frags, defer-max THR=8.

typedef unsigned short u16;
typedef unsigned int   u32;
typedef short short8   __attribute__((ext_vector_type(8)));
typedef float floatx16 __attribute__((ext_vector_type(16)));
typedef u32 u32x4      __attribute__((ext_vector_type(4)));

#define B_ 4
#define L_ 2048
#define S_ 2048
#define H_ 8
#define E_ 64
#define D_ 64

// round-half-up fp32->bf16 pair, lo in low 16 bits
static __device__ __forceinline__ u32 pack2(float lo, float hi) {
    const u32 a = __float_as_uint(lo) + 0x8000u;
    const u32 b = __float_as_uint(hi) + 0x8000u;
    return __builtin_amdgcn_perm(b, a, 0x07060302u);
}
static __device__ __forceinline__ u16 bf16c(float x) {
    return (u16)((__float_as_uint(x) + 0x8000u) >> 16);
}
// v_permlane32_swap_b32: a.hi32lanes <-> b.lo32lanes
static __device__ __forceinline__ void pl32swap(u32& a, u32& b) {
    asm("v_permlane32_swap_b32 %0, %1" : "+v"(a), "+v"(b));
}
static __device__ __forceinline__ floatx16 zero16() {
    floatx16 z;
    #pragma unroll
    for (int i = 0; i < 16; i++) z[i] = 0.f;
    return z;
}
// async 16B-per-lane global -> LDS (dest = uniform base + lane*16)
static __device__ __forceinline__ void gload_lds16(u16* lds, const u16* g) {
    __builtin_amdgcn_global_load_lds((const __attribute__((address_space(1))) void*)g,
                                     (__attribute__((address_space(3))) void*)lds,
                                     16, 0, 0);
}

// ---------------- pre-pass: fp32 -> bf16, FRAG-MAJOR tiles ----------------
// Kc tile (per bh,kt; 4096 u16): [F=mt*4+ks][lane=hi*32+l31][j]
//   holds K[b][s=kt*64+mt*32+l31][h][e=ks*16+hi*8+j]
// Vt tile (per bh,kt; 4096 u16): [F=nt*4+ks][lane=hi*32+l31][j]
//   holds V[b][s=kt*64+ks*16+hi*8+j][h][d=nt*32+l31]
__global__ __launch_bounds__(256)
void cvt_kernel(const float* __restrict__ k, const float* __restrict__ v,
                u16* __restrict__ kc, u16* __restrict__ vt)
{
    __shared__ u16 Lt[64 * 72];
    const int bx = blockIdx.x, t = threadIdx.x;
    const int tile = bx & 1023;
    const int kt = tile & 31, h = (tile >> 5) & 7, b = tile >> 8;
    const int F  = t >> 5;
    const int hi = (t >> 4) & 1;
    const int l0 = (t & 15) * 2;

    if (bx < 1024) {
        const int mt = F >> 2, ks = F & 3;
        const int s  = kt * 64 + mt * 32 + l0;
        const int e  = ks * 16 + hi * 8;
        const float* p0 = k + (((size_t)(b * S_ + s)) * H_ + h) * E_ + e;
        const float4 a0 = ((const float4*)p0)[0], a1 = ((const float4*)p0)[1];
        const float* p1 = p0 + H_ * E_;
        const float4 b0 = ((const float4*)p1)[0], b1 = ((const float4*)p1)[1];
        u16* dst = kc + ((size_t)(b * 8 + h)) * 131072 + (size_t)kt * 4096 + t * 16;
        *(u32x4*)dst = (u32x4){pack2(a0.x, a0.y), pack2(a0.z, a0.w),
                               pack2(a1.x, a1.y), pack2(a1.z, a1.w)};
        *(u32x4*)(dst + 8) = (u32x4){pack2(b0.x, b0.y), pack2(b0.z, b0.w),
                                     pack2(b1.x, b1.y), pack2(b1.z, b1.w)};
    } else {
        {
            const int i  = t >> 2;
            const int d0 = (t & 3) * 16;
            const float* vp = v + (((size_t)(b * S_ + kt * 64 + i)) * H_ + h) * D_ + d0;
            const float4 a0 = ((const float4*)vp)[0], a1 = ((const float4*)vp)[1];
            const float4 a2 = ((const float4*)vp)[2], a3 = ((const float4*)vp)[3];
            const float va[16] = {a0.x,a0.y,a0.z,a0.w, a1.x,a1.y,a1.z,a1.w,
                                  a2.x,a2.y,a2.z,a2.w, a3.x,a3.y,a3.z,a3.w};
            #pragma unroll
            for (int jj = 0; jj < 16; jj++) Lt[(d0 + jj) * 72 + i] = bf16c(va[jj]);
        }
        __syncthreads();
        {
            const int nt = F >> 2, ks = F & 3;
            const int d1 = nt * 32 + l0;
            u16* dst = vt + ((size_t)(b * 8 + h)) * 131072 + (size_t)kt * 4096 + t * 16;
            *(u32x4*)dst       = *(const u32x4*)&Lt[(d1    ) * 72 + ks * 16 + hi * 8];
            *(u32x4*)(dst + 8) = *(const u32x4*)&Lt[(d1 + 1) * 72 + ks * 16 + hi * 8];
        }
    }
}

// ---------------- main kernel ----------------
// Grid 512 x 256thr. bx bits: [0:2]=h, [3:4]=b, [5:7]=idx, [8]=half.
// j = half ? idx : 15-idx  -> each CU hosts one long + one short block
// (34 tiles/CU, balanced). Wave w -> rows q0 = 128j+32w .. +31.
// All waves iterate kt = 0..2j+1 over shared LDS-staged K/V tiles.
template<int SRC>
__global__ __launch_bounds__(256, 2)
void fa_kernel(const float* __restrict__ q, const float* __restrict__ kk,
               const float* __restrict__ vv, const u16* __restrict__ kc,
               const u16* __restrict__ vt, float* __restrict__ out)
{
    __shared__ __align__(16) u16 KV[2][8192];   // [buf][K 8 frags | V 8 frags]

    const int tid  = threadIdx.x;
    const int w    = tid >> 6;
    const int lane = tid & 63;
    const int l31  = lane & 31;
    const int hi   = lane >> 5;

    const int bx   = blockIdx.x;
    const int h    = bx & 7;
    const int b    = (bx >> 3) & 3;
    const int idx  = (bx >> 5) & 7;
    const int j    = (bx >> 8) ? idx : (15 - idx);
    const int q0   = 128 * j + 32 * w;
    const int ktend = 2 * j + 1;
    const int qlim = q0 + 31;            // last q-row this wave owns
    const int dt   = (q0 + 31) >> 6;     // first tile needing the causal mask

    const float kscale = 0.18033688011112042f; // (1/sqrt(64)) * log2(e)

    // ---- Q frags (B-operand of S^T = K*Q^T), kscale folded ----
    const float* qptr = q + (((size_t)b * L_ + q0 + l31) * H_ + h) * E_ + hi * 8;
    short8 qf[4];
    #pragma unroll
    for (int ks = 0; ks < 4; ks++) {
        const float4 a0 = *(const float4*)(qptr + ks * 16);
        const float4 a1 = *(const float4*)(qptr + ks * 16 + 4);
        const u32x4 u = {pack2(a0.x * kscale, a0.y * kscale), pack2(a0.z * kscale, a0.w * kscale),
                         pack2(a1.x * kscale, a1.y * kscale), pack2(a1.z * kscale, a1.w * kscale)};
        qf[ks] = __builtin_bit_cast(short8, u);
    }

    const size_t bh = (size_t)(b * 8 + h);
    const u16* kcb = kc + bh * 131072;
    const u16* vtb = vt + bh * 131072;

    // async stage: wave w moves K frags {2w,2w+1} and V frags {2w,2w+1}
    auto stage = [&](int kt, int bufi) {
        #pragma unroll
        for (int ff = 0; ff < 2; ff++) {
            const int f = w * 2 + ff;
            gload_lds16(&KV[bufi][f * 512],        kcb + (size_t)kt * 4096 + f * 512 + lane * 8);
            gload_lds16(&KV[bufi][4096 + f * 512], vtb + (size_t)kt * 4096 + f * 512 + lane * 8);
        }
    };
    // sync fallback stage (no workspace): fp32 loads + pack + ds_write
    auto stage_sync = [&](int kt) {
        #pragma unroll
        for (int ff = 0; ff < 2; ff++) {
            const int f = w * 2 + ff;
            const int mt = f >> 2, ks = f & 3;
            const float* p = kk + (((size_t)b * S_ + kt * 64 + mt * 32 + l31) * H_ + h) * E_ + ks * 16 + hi * 8;
            const float4 a0 = *(const float4*)p;
            const float4 a1 = *(const float4*)(p + 4);
            *(u32x4*)&KV[0][f * 512 + lane * 8] =
                (u32x4){pack2(a0.x, a0.y), pack2(a0.z, a0.w), pack2(a1.x, a1.y), pack2(a1.z, a1.w)};
            float fv[8];
            #pragma unroll
            for (int jj = 0; jj < 8; jj++)
                fv[jj] = vv[(((size_t)b * S_ + kt * 64 + ks * 16 + hi * 8 + jj) * H_ + h) * D_ + mt * 32 + l31];
            *(u32x4*)&KV[0][4096 + f * 512 + lane * 8] =
                (u32x4){pack2(fv[0], fv[1]), pack2(fv[2], fv[3]), pack2(fv[4], fv[5]), pack2(fv[6], fv[7])};
        }
    };

    floatx16 occ[2] = {zero16(), zero16()};  // O^T: col = q = l31
    float m_run = -1e30f, l_run = 0.f;

    // ---- prologue ----
    if constexpr (SRC == 0) {
        stage(0, 0);
        asm volatile("s_waitcnt vmcnt(0)" ::: "memory");
        __builtin_amdgcn_s_barrier();
        __builtin_amdgcn_sched_barrier(0);   // first-tile reads stay below
    }

    for (int kt = 0; kt <= ktend; kt++) {
        int cur;
        if constexpr (SRC == 0) {
            cur = kt & 1;
            if (kt < ktend) {
                stage(kt + 1, cur ^ 1);                            // async, in flight
                asm volatile("s_waitcnt vmcnt(4)" ::: "memory");   // tile kt's 4 done
            } else {
                asm volatile("s_waitcnt vmcnt(0)" ::: "memory");
            }
            __builtin_amdgcn_s_barrier();                          // tile kt in LDS
            __builtin_amdgcn_sched_barrier(0);                     // no hoist above sync
        } else {
            cur = 0;
            stage_sync(kt);
            __syncthreads();
        }

        // fully-masked tile for this wave? keep barriers, skip compute
        if (kt * 64 <= qlim) {
            // ---- load 16 frags from LDS (lane-linear ds_read_b128) ----
            short8 kfr[2][4], vfr[2][4];
            #pragma unroll
            for (int mt = 0; mt < 2; mt++)
                #pragma unroll
                for (int ks = 0; ks < 4; ks++) {
                    kfr[mt][ks] = *(const short8*)&KV[cur][(mt * 4 + ks) * 512 + lane * 8];
                    vfr[mt][ks] = *(const short8*)&KV[cur][4096 + (mt * 4 + ks) * 512 + lane * 8];
                }

            // ---- S^T = K*Q^T ----
            floatx16 sac[2];
            __builtin_amdgcn_s_setprio(1);
            #pragma unroll
            for (int mt = 0; mt < 2; mt++) {
                floatx16 c = zero16();
                #pragma unroll
                for (int ks = 0; ks < 4; ks++)
                    c = __builtin_amdgcn_mfma_f32_32x32x16_bf16(kfr[mt][ks], qf[ks], c, 0, 0, 0);
                sac[mt] = c;
            }
            __builtin_amdgcn_s_setprio(0);

            // ---- causal mask from the diagonal tile on (kt >= dt) ----
            if (kt >= dt) {
                const int qg = q0 + l31;
                #pragma unroll
                for (int mt = 0; mt < 2; mt++)
                    #pragma unroll
                    for (int r = 0; r < 16; r++) {
                        const int keyg = kt * 64 + mt * 32 + (r & 3) + (r >> 2) * 8 + hi * 4;
                        if (keyg > qg) sac[mt][r] = -1e30f;
                    }
            }

            // ---- online softmax, in-lane + 1 shfl; defer-max (THR=8) ----
            float red[16];
            #pragma unroll
            for (int r = 0; r < 16; r++) red[r] = fmaxf(sac[0][r], sac[1][r]);
            #pragma unroll
            for (int stp = 8; stp > 0; stp >>= 1)
                #pragma unroll
                for (int r = 0; r < stp; r++) red[r] = fmaxf(red[r], red[r + stp]);
            const float mx = fmaxf(red[0], __shfl_xor(red[0], 32));

            const bool defer = __all(mx - m_run <= 8.0f) != 0;
            if (!defer) {
                const float mnew  = fmaxf(m_run, mx);
                const float alpha = exp2f(m_run - mnew);
                m_run = mnew;
                l_run *= alpha;
                #pragma unroll
                for (int r = 0; r < 16; r++) { occ[0][r] *= alpha; occ[1][r] *= alpha; }
            }

            float sum[16];
            #pragma unroll
            for (int r = 0; r < 16; r++) {
                sac[0][r] = exp2f(sac[0][r] - m_run);
                sac[1][r] = exp2f(sac[1][r] - m_run);
                sum[r] = sac[0][r] + sac[1][r];
            }
            #pragma unroll
            for (int stp = 8; stp > 0; stp >>= 1)
                #pragma unroll
                for (int r = 0; r < stp; r++) sum[r] += sum[r + stp];
            l_run += sum[0] + __shfl_xor(sum[0], 32);

            // ---- P -> bf16 pairs ----
            u32 pk0[8], pk1[8];
            #pragma unroll
            for (int r2 = 0; r2 < 4; r2++) {
                pk0[2 * r2 + 0] = pack2(sac[0][4 * r2 + 0], sac[0][4 * r2 + 1]);
                pk0[2 * r2 + 1] = pack2(sac[0][4 * r2 + 2], sac[0][4 * r2 + 3]);
                pk1[2 * r2 + 0] = pack2(sac[1][4 * r2 + 0], sac[1][4 * r2 + 1]);
                pk1[2 * r2 + 1] = pack2(sac[1][4 * r2 + 2], sac[1][4 * r2 + 3]);
            }

            // ---- O^T += V^T * P (permlane32_swap builds B-frags) ----
            __builtin_amdgcn_s_setprio(1);
            #pragma unroll
            for (int ks = 0; ks < 4; ks++) {
                const int u = (ks & 1) * 4;
                u32 w0, w1, w2, w3;
                if (ks < 2) { w0 = pk0[u]; w1 = pk0[u + 1]; w2 = pk0[u + 2]; w3 = pk0[u + 3]; }
                else        { w0 = pk1[u]; w1 = pk1[u + 1]; w2 = pk1[u + 2]; w3 = pk1[u + 3]; }
                pl32swap(w0, w2);
                pl32swap(w1, w3);
                const u32x4 pw = {w0, w1, w2, w3};
                const short8 pf = __builtin_bit_cast(short8, pw);
                occ[0] = __builtin_amdgcn_mfma_f32_32x32x16_bf16(vfr[0][ks], pf, occ[0], 0, 0, 0);
                occ[1] = __builtin_amdgcn_mfma_f32_32x32x16_bf16(vfr[1][ks], pf, occ[1], 0, 0, 0);
            }
            __builtin_amdgcn_s_setprio(0);
        }

        // ---- end-of-tile barrier: everyone done reading KV[cur] ----
        if constexpr (SRC == 0) {
            __builtin_amdgcn_sched_barrier(0);   // no sink below into next tile
            __builtin_amdgcn_s_barrier();
        } else {
            __syncthreads();
        }
    }

    // ---- epilogue: O = O^T / l ----
    const float inv = 1.0f / l_run;
    float* op = out + (((size_t)b * L_ + q0 + l31) * H_ + h) * D_;
    #pragma unroll
    for (int nt = 0; nt < 2; nt++)
        #pragma unroll
        for (int r2 = 0; r2 < 4; r2++) {
            const float4 o = {occ[nt][4 * r2 + 0] * inv, occ[nt][4 * r2 + 1] * inv,
                              occ[nt][4 * r2 + 2] * inv, occ[nt][4 * r2 + 3] * inv};
            *(float4*)(op + nt * 32 + r2 * 8 + hi * 4) = o;
        }
}

extern "C" void kernel_launch(void* const* d_in, const int* in_sizes, int n_in,
                              void* d_out, int out_size, void* d_ws, size_t ws_size,
                              hipStream_t stream) {
    const float* q = (const float*)d_in[0];
    const float* k = (const float*)d_in[1];
    const float* v = (const float*)d_in[2];
    // d_in[3] = attn_mask: fixed causal triu -> handled analytically in-kernel.
    float* out = (float*)d_out;

    const size_t elems = (size_t)B_ * H_ * S_ * E_;   // per tensor (u16 count)
    const size_t need  = elems * 2 * 2;               // Kc + Vt, bf16
    if (d_ws != nullptr && ws_size >= need) {
        u16* kc = (u16*)d_ws;
        u16* vt = kc + elems;
        cvt_kernel<<<dim3(2048), dim3(256), 0, stream>>>(k, v, kc, vt);
        fa_kernel<0><<<dim3(512), dim3(256), 0, stream>>>(q, k, v, kc, vt, out);
    } else {
        fa_kernel<1><<<dim3(512), dim3(256), 0, stream>>>(q, k, v, nullptr, nullptr, out);
    }
}